// Round 14
// baseline (243.635 us; speedup 1.0000x reference)
//
#include <hip/hip_runtime.h>
#include <hip/hip_fp16.h>

#define N_NODES 100000
#define N_EDGES 1600000
#define F_IN 128
#define HID 64
#define NG 128

#define GEMB 1563    // 64-row gemm tiles
#define NBINS 1024   // buckets = dst>>7 (782 used)
#define NBLK  391    // pass-A blocks, 4096 edges each
#define BUCKETS 782  // ceil(100000/128)
#define CNTB 391

#define FMA_ROW(acc, xv) \
    acc.x = fmaf(xv.x, w0.x, acc.x); acc.y = fmaf(xv.x, w0.y, acc.y); \
    acc.z = fmaf(xv.x, w0.z, acc.z); acc.w = fmaf(xv.x, w0.w, acc.w); \
    acc.x = fmaf(xv.y, w1.x, acc.x); acc.y = fmaf(xv.y, w1.y, acc.y); \
    acc.z = fmaf(xv.y, w1.z, acc.z); acc.w = fmaf(xv.y, w1.w, acc.w); \
    acc.x = fmaf(xv.z, w2.x, acc.x); acc.y = fmaf(xv.z, w2.y, acc.y); \
    acc.z = fmaf(xv.z, w2.z, acc.z); acc.w = fmaf(xv.z, w2.w, acc.w); \
    acc.x = fmaf(xv.w, w3.x, acc.x); acc.y = fmaf(xv.w, w3.y, acc.y); \
    acc.z = fmaf(xv.w, w3.z, acc.z); acc.w = fmaf(xv.w, w3.w, acc.w);

#define FMA_EDGE(hh, ww) \
    acc.x = fmaf(hh.x, ww, acc.x); acc.y = fmaf(hh.y, ww, acc.y); \
    acc.z = fmaf(hh.z, ww, acc.z); acc.w = fmaf(hh.w, ww, acc.w);

#define ADD_EDGE(hh) \
    acc.x += hh.x; acc.y += hh.y; acc.z += hh.z; acc.w += hh.w;

__device__ __forceinline__ float4 ldh4(const __half* p) {
    uint2 u = *(const uint2*)p;
    __half2 a = *(__half2*)&u.x, b = *(__half2*)&u.y;
    float2 fa = __half22float2(a), fb = __half22float2(b);
    return make_float4(fa.x, fa.y, fb.x, fb.y);
}
__device__ __forceinline__ void sth4(__half* p, float4 v) {
    __half2 a = __floats2half2_rn(v.x, v.y), b = __floats2half2_rn(v.z, v.w);
    uint2 u; u.x = *(unsigned int*)&a; u.y = *(unsigned int*)&b;
    *(uint2*)p = u;
}

__device__ __forceinline__ float4 gather_row_w(const __half* __restrict__ h16,
                                               const int* __restrict__ eidx,
                                               const float* __restrict__ dinv,
                                               int e0, int e1, int c4) {
    float4 acc = make_float4(0.f, 0.f, 0.f, 0.f);
    int e = e0;
    for (; e + 7 < e1; e += 8) {
        int s0 = eidx[e],     s1 = eidx[e + 1], s2 = eidx[e + 2], s3 = eidx[e + 3];
        int s4 = eidx[e + 4], s5 = eidx[e + 5], s6 = eidx[e + 6], s7 = eidx[e + 7];
        float w0 = dinv[s0], w1 = dinv[s1], w2 = dinv[s2], w3 = dinv[s3];
        float w4 = dinv[s4], w5 = dinv[s5], w6 = dinv[s6], w7 = dinv[s7];
        float4 h0 = ldh4(&h16[(size_t)s0 * HID + c4]);
        float4 h1 = ldh4(&h16[(size_t)s1 * HID + c4]);
        float4 h2 = ldh4(&h16[(size_t)s2 * HID + c4]);
        float4 h3 = ldh4(&h16[(size_t)s3 * HID + c4]);
        float4 h4 = ldh4(&h16[(size_t)s4 * HID + c4]);
        float4 h5 = ldh4(&h16[(size_t)s5 * HID + c4]);
        float4 h6 = ldh4(&h16[(size_t)s6 * HID + c4]);
        float4 h7 = ldh4(&h16[(size_t)s7 * HID + c4]);
        FMA_EDGE(h0, w0); FMA_EDGE(h1, w1); FMA_EDGE(h2, w2); FMA_EDGE(h3, w3);
        FMA_EDGE(h4, w4); FMA_EDGE(h5, w5); FMA_EDGE(h6, w6); FMA_EDGE(h7, w7);
    }
    if (e + 3 < e1) {
        int s0 = eidx[e], s1 = eidx[e + 1], s2 = eidx[e + 2], s3 = eidx[e + 3];
        float w0 = dinv[s0], w1 = dinv[s1], w2 = dinv[s2], w3 = dinv[s3];
        float4 h0 = ldh4(&h16[(size_t)s0 * HID + c4]);
        float4 h1 = ldh4(&h16[(size_t)s1 * HID + c4]);
        float4 h2 = ldh4(&h16[(size_t)s2 * HID + c4]);
        float4 h3 = ldh4(&h16[(size_t)s3 * HID + c4]);
        FMA_EDGE(h0, w0); FMA_EDGE(h1, w1); FMA_EDGE(h2, w2); FMA_EDGE(h3, w3);
        e += 4;
    }
    for (; e < e1; ++e) {
        int s0 = eidx[e];
        float w0 = dinv[s0];
        float4 h0 = ldh4(&h16[(size_t)s0 * HID + c4]);
        FMA_EDGE(h0, w0);
    }
    return acc;
}

__device__ __forceinline__ float4 gather_row_nw(const __half* __restrict__ h16,
                                                const int* __restrict__ eidx,
                                                int e0, int e1, int c4) {
    float4 acc = make_float4(0.f, 0.f, 0.f, 0.f);
    int e = e0;
    for (; e + 7 < e1; e += 8) {
        int s0 = eidx[e],     s1 = eidx[e + 1], s2 = eidx[e + 2], s3 = eidx[e + 3];
        int s4 = eidx[e + 4], s5 = eidx[e + 5], s6 = eidx[e + 6], s7 = eidx[e + 7];
        float4 h0 = ldh4(&h16[(size_t)s0 * HID + c4]);
        float4 h1 = ldh4(&h16[(size_t)s1 * HID + c4]);
        float4 h2 = ldh4(&h16[(size_t)s2 * HID + c4]);
        float4 h3 = ldh4(&h16[(size_t)s3 * HID + c4]);
        float4 h4 = ldh4(&h16[(size_t)s4 * HID + c4]);
        float4 h5 = ldh4(&h16[(size_t)s5 * HID + c4]);
        float4 h6 = ldh4(&h16[(size_t)s6 * HID + c4]);
        float4 h7 = ldh4(&h16[(size_t)s7 * HID + c4]);
        ADD_EDGE(h0); ADD_EDGE(h1); ADD_EDGE(h2); ADD_EDGE(h3);
        ADD_EDGE(h4); ADD_EDGE(h5); ADD_EDGE(h6); ADD_EDGE(h7);
    }
    if (e + 3 < e1) {
        int s0 = eidx[e], s1 = eidx[e + 1], s2 = eidx[e + 2], s3 = eidx[e + 3];
        float4 h0 = ldh4(&h16[(size_t)s0 * HID + c4]);
        float4 h1 = ldh4(&h16[(size_t)s1 * HID + c4]);
        float4 h2 = ldh4(&h16[(size_t)s2 * HID + c4]);
        float4 h3 = ldh4(&h16[(size_t)s3 * HID + c4]);
        ADD_EDGE(h0); ADD_EDGE(h1); ADD_EDGE(h2); ADD_EDGE(h3);
        e += 4;
    }
    for (; e < e1; ++e) {
        int s0 = eidx[e];
        float4 h0 = ldh4(&h16[(size_t)s0 * HID + c4]);
        ADD_EDGE(h0);
    }
    return acc;
}

template <int K>
__device__ __forceinline__ void gemm_tile(const float* __restrict__ X,
                                          const float* __restrict__ W,
                                          __half* __restrict__ H16,
                                          int tile, float* smem) {
    const int tid = threadIdx.x;
    const int rg  = tid >> 4;
    const int c4  = (tid & 15) * 4;
    const int r0  = tile * 64 + rg * 4;
    const bool full = (r0 + 3 < N_NODES);

    float4 a0 = {0,0,0,0}, a1 = {0,0,0,0}, a2 = {0,0,0,0}, a3 = {0,0,0,0};

    for (int kh = 0; kh < K; kh += 64) {
        __syncthreads();
        for (int i = tid; i < 1024; i += 256)
            ((float4*)smem)[i] = ((const float4*)(W + kh * 64))[i];
        __syncthreads();

        const float* Xb = X + (size_t)r0 * K + kh;
        #pragma unroll 4
        for (int k2 = 0; k2 < 64; k2 += 4) {
            float4 w0 = *(float4*)&smem[(k2 + 0) * 64 + c4];
            float4 w1 = *(float4*)&smem[(k2 + 1) * 64 + c4];
            float4 w2 = *(float4*)&smem[(k2 + 2) * 64 + c4];
            float4 w3 = *(float4*)&smem[(k2 + 3) * 64 + c4];
            float4 x0 = {0,0,0,0}, x1 = {0,0,0,0}, x2 = {0,0,0,0}, x3 = {0,0,0,0};
            if (full) {
                x0 = *(const float4*)&Xb[0 * (size_t)K + k2];
                x1 = *(const float4*)&Xb[1 * (size_t)K + k2];
                x2 = *(const float4*)&Xb[2 * (size_t)K + k2];
                x3 = *(const float4*)&Xb[3 * (size_t)K + k2];
            } else {
                if (r0 + 0 < N_NODES) x0 = *(const float4*)&Xb[0 * (size_t)K + k2];
                if (r0 + 1 < N_NODES) x1 = *(const float4*)&Xb[1 * (size_t)K + k2];
                if (r0 + 2 < N_NODES) x2 = *(const float4*)&Xb[2 * (size_t)K + k2];
                if (r0 + 3 < N_NODES) x3 = *(const float4*)&Xb[3 * (size_t)K + k2];
            }
            FMA_ROW(a0, x0);
            FMA_ROW(a1, x1);
            FMA_ROW(a2, x2);
            FMA_ROW(a3, x3);
        }
    }

    if (full) {
        sth4(&H16[(size_t)(r0 + 0) * HID + c4], a0);
        sth4(&H16[(size_t)(r0 + 1) * HID + c4], a1);
        sth4(&H16[(size_t)(r0 + 2) * HID + c4], a2);
        sth4(&H16[(size_t)(r0 + 3) * HID + c4], a3);
    } else {
        if (r0 + 0 < N_NODES) sth4(&H16[(size_t)(r0 + 0) * HID + c4], a0);
        if (r0 + 1 < N_NODES) sth4(&H16[(size_t)(r0 + 1) * HID + c4], a1);
        if (r0 + 2 < N_NODES) sth4(&H16[(size_t)(r0 + 2) * HID + c4], a2);
        if (r0 + 3 < N_NODES) sth4(&H16[(size_t)(r0 + 3) * HID + c4], a3);
    }
}

// ---- fused front: [gemm1 | LDS bucket-count (no global atomics) | batch counts] ----
__global__ __launch_bounds__(256) void k_front(const int* __restrict__ dst,
                                               int* __restrict__ hist,   // [NBINS][NBLK]
                                               const int* __restrict__ batch,
                                               int* __restrict__ gcnt,
                                               const float* __restrict__ X,
                                               const float* __restrict__ W,
                                               __half* __restrict__ H16) {
    __shared__ float smem[4096];   // 16 KB
    int bid = blockIdx.x;
    int tid = threadIdx.x;
    if (bid < GEMB) {
        gemm_tile<F_IN>(X, W, H16, bid, smem);
    } else if (bid < GEMB + NBLK) {
        int cb = bid - GEMB;
        int* bins = (int*)smem;
        for (int i = tid; i < NBINS; i += 256) bins[i] = 0;
        __syncthreads();
        #pragma unroll
        for (int it = 0; it < 4; ++it) {
            int base = cb * 4096 + it * 1024 + tid * 4;
            if (base < N_EDGES) {
                int4 d4 = *(const int4*)&dst[base];
                atomicAdd(&bins[d4.x >> 7], 1);
                atomicAdd(&bins[d4.y >> 7], 1);
                atomicAdd(&bins[d4.z >> 7], 1);
                atomicAdd(&bins[d4.w >> 7], 1);
            }
        }
        __syncthreads();
        for (int i = tid; i < NBINS; i += 256) hist[(size_t)i * NBLK + cb] = bins[i];
    } else {
        int* bins = (int*)smem;
        if (tid < NG) bins[tid] = 0;
        __syncthreads();
        int i = (bid - GEMB - NBLK) * 256 + tid;
        if (i < N_NODES) atomicAdd(&bins[batch[i]], 1);
        __syncthreads();
        if (tid < NG && bins[tid] != 0) atomicAdd(&gcnt[tid], bins[tid]);
    }
}

// ---- scan L1: 391 blocks x 1024 over hist (400384 = 391*1024 exactly) ----
__global__ __launch_bounds__(1024) void k_bsum(const int* __restrict__ hist,
                                               int* __restrict__ bsum) {
    __shared__ int red[1024];
    int i = blockIdx.x * 1024 + threadIdx.x;
    red[threadIdx.x] = hist[i];
    __syncthreads();
    for (int off = 512; off > 0; off >>= 1) {
        if (threadIdx.x < off) red[threadIdx.x] += red[threadIdx.x + off];
        __syncthreads();
    }
    if (threadIdx.x == 0) bsum[blockIdx.x] = red[0];
}

__global__ __launch_bounds__(512) void k_scanb(const int* __restrict__ bsum,
                                               int* __restrict__ boff, int nb) {
    __shared__ int tmp[512];
    int t = threadIdx.x;
    int v = (t < nb) ? bsum[t] : 0;
    tmp[t] = v;
    __syncthreads();
    for (int off = 1; off < 512; off <<= 1) {
        int u = (t >= off) ? tmp[t - off] : 0;
        __syncthreads();
        tmp[t] += u;
        __syncthreads();
    }
    if (t < nb) boff[t] = tmp[t] - v;
}

// ---- scan L3: in-place exclusive scan of hist; emit bucketstart ----
__global__ __launch_bounds__(1024) void k_scanfin(int* __restrict__ hist,
                                                  const int* __restrict__ boff,
                                                  int* __restrict__ bucketstart) {
    __shared__ int tmp[1024];
    int i = blockIdx.x * 1024 + threadIdx.x;
    int t = threadIdx.x;
    int v = hist[i];
    tmp[t] = v;
    __syncthreads();
    for (int off = 1; off < 1024; off <<= 1) {
        int u = (t >= off) ? tmp[t - off] : 0;
        __syncthreads();
        tmp[t] += u;
        __syncthreads();
    }
    int excl = boff[blockIdx.x] + tmp[t] - v;
    hist[i] = excl;
    if (i % NBLK == 0) bucketstart[i / NBLK] = excl;   // i = bin*NBLK
}

// ---- scatter: LDS cursors (atomic-return in LDS only) -> bucket-grouped recs ----
__global__ __launch_bounds__(256) void k_scatter(const int* __restrict__ src,
                                                 const int* __restrict__ dst,
                                                 const int* __restrict__ hist,
                                                 int* __restrict__ ebuf) {
    __shared__ int cur[NBINS];
    int cb = blockIdx.x;
    int tid = threadIdx.x;
    for (int i = tid; i < NBINS; i += 256) cur[i] = hist[(size_t)i * NBLK + cb];
    __syncthreads();
    #pragma unroll
    for (int it = 0; it < 4; ++it) {
        int base = cb * 4096 + it * 1024 + tid * 4;
        if (base < N_EDGES) {
            int4 s4 = *(const int4*)&src[base];
            int4 d4 = *(const int4*)&dst[base];
            int p0 = atomicAdd(&cur[d4.x >> 7], 1);
            int p1 = atomicAdd(&cur[d4.y >> 7], 1);
            int p2 = atomicAdd(&cur[d4.z >> 7], 1);
            int p3 = atomicAdd(&cur[d4.w >> 7], 1);
            ebuf[p0] = (s4.x << 7) | (d4.x & 127);
            ebuf[p1] = (s4.y << 7) | (d4.y & 127);
            ebuf[p2] = (s4.z << 7) | (d4.z & 127);
            ebuf[p3] = (s4.w << 7) | (d4.w & 127);
        }
    }
}

// ---- per-bucket CSR: stage recs in LDS, count/scan 128 nodes, place in-place ----
__global__ __launch_bounds__(256) void k_bucketcsr(int* __restrict__ eidx,   // = ebuf
                                                   const int* __restrict__ bucketstart,
                                                   int* __restrict__ rowptr,
                                                   float* __restrict__ dinv) {
    __shared__ int lrec[4096];
    __shared__ int lcnt[128];
    __shared__ int lsum[128];
    __shared__ int lcur[128];
    int b = blockIdx.x;
    int tid = threadIdx.x;
    int s0 = bucketstart[b], s1 = bucketstart[b + 1];
    int cnt = s1 - s0;

    if (tid < 128) lcnt[tid] = 0;
    __syncthreads();
    for (int i = tid; i < cnt; i += 256) {
        int r = eidx[s0 + i];
        lrec[i] = r;
        atomicAdd(&lcnt[r & 127], 1);
    }
    __syncthreads();
    if (tid < 128) lsum[tid] = lcnt[tid];
    __syncthreads();
    for (int off = 1; off < 128; off <<= 1) {
        int u = 0;
        if (tid < 128 && tid >= off) u = lsum[tid - off];
        __syncthreads();
        if (tid < 128) lsum[tid] += u;
        __syncthreads();
    }
    if (tid < 128) {
        int excl = lsum[tid] - lcnt[tid];
        lcur[tid] = s0 + excl;
        int node = b * 128 + tid;
        if (node < N_NODES) {
            rowptr[node] = s0 + excl;
            dinv[node] = 1.0f / sqrtf((float)lcnt[tid] + 1.0f);
        }
    }
    __syncthreads();
    for (int i = tid; i < cnt; i += 256) {
        int r = lrec[i];
        int p = atomicAdd(&lcur[r & 127], 1);
        eidx[p] = r >> 7;
    }
    if (b == 0 && tid == 0) rowptr[N_NODES] = N_EDGES;
}

// ---- fused: gather L1 -> relu -> fp16 LDS -> gemm x W2(fp16 LDS) -> pre-scaled fp16 ----
// LDS cut 33->17KB (R13: occupancy 31% was the gather-BW limiter)
__global__ __launch_bounds__(256) void k_gathergemm(const __half* __restrict__ h16,
                                                    const int* __restrict__ eidx,
                                                    const int* __restrict__ rowptr,
                                                    const float* __restrict__ dinv,
                                                    const float* __restrict__ bias,
                                                    const float* __restrict__ W2,
                                                    __half* __restrict__ Hout16) {
    __shared__ __half Xl[64][72];      // 9 KB, fp16, pad 8
    __shared__ __half Wl[64 * 64];     // 8 KB, fp16
    const int tid  = threadIdx.x;
    const int ng4  = tid >> 4;
    const int tile = blockIdx.x;
    const int c4   = (tid & 15) * 4;

    // stage W2 as fp16 (float4 -> half4) while gather loads are in flight
    for (int i = tid; i < 1024; i += 256) {
        float4 v = ((const float4*)W2)[i];
        sth4(&Wl[i * 4], v);
    }

    float4 b = *(const float4*)&bias[c4];
    #pragma unroll
    for (int j = 0; j < 4; ++j) {
        int node = tile * 64 + ng4 * 4 + j;
        float4 r = make_float4(0.f, 0.f, 0.f, 0.f);
        if (node < N_NODES) {
            int e0 = rowptr[node], e1 = rowptr[node + 1];
            float4 acc = gather_row_w(h16, eidx, dinv, e0, e1, c4);
            float di = dinv[node];
            float4 hd = ldh4(&h16[(size_t)node * HID + c4]);
            r.x = fmaxf(fmaf(di, fmaf(di, hd.x, acc.x), b.x), 0.f);
            r.y = fmaxf(fmaf(di, fmaf(di, hd.y, acc.y), b.y), 0.f);
            r.z = fmaxf(fmaf(di, fmaf(di, hd.z, acc.z), b.z), 0.f);
            r.w = fmaxf(fmaf(di, fmaf(di, hd.w, acc.w), b.w), 0.f);
        }
        sth4(&Xl[ng4 * 4 + j][c4], r);
    }
    __syncthreads();

    float4 a0 = {0,0,0,0}, a1 = {0,0,0,0}, a2 = {0,0,0,0}, a3 = {0,0,0,0};
    #pragma unroll 4
    for (int k2 = 0; k2 < 64; k2 += 4) {
        float4 w0 = ldh4(&Wl[(k2 + 0) * 64 + c4]);
        float4 w1 = ldh4(&Wl[(k2 + 1) * 64 + c4]);
        float4 w2 = ldh4(&Wl[(k2 + 2) * 64 + c4]);
        float4 w3 = ldh4(&Wl[(k2 + 3) * 64 + c4]);
        float4 x0 = ldh4(&Xl[ng4 * 4 + 0][k2]);
        float4 x1 = ldh4(&Xl[ng4 * 4 + 1][k2]);
        float4 x2 = ldh4(&Xl[ng4 * 4 + 2][k2]);
        float4 x3 = ldh4(&Xl[ng4 * 4 + 3][k2]);
        FMA_ROW(a0, x0);
        FMA_ROW(a1, x1);
        FMA_ROW(a2, x2);
        FMA_ROW(a3, x3);
    }

    const int r0 = tile * 64 + ng4 * 4;
    if (r0 + 0 < N_NODES) { float d0 = dinv[r0 + 0];
        a0.x *= d0; a0.y *= d0; a0.z *= d0; a0.w *= d0;
        sth4(&Hout16[(size_t)(r0 + 0) * HID + c4], a0); }
    if (r0 + 1 < N_NODES) { float d1 = dinv[r0 + 1];
        a1.x *= d1; a1.y *= d1; a1.z *= d1; a1.w *= d1;
        sth4(&Hout16[(size_t)(r0 + 1) * HID + c4], a1); }
    if (r0 + 2 < N_NODES) { float d2 = dinv[r0 + 2];
        a2.x *= d2; a2.y *= d2; a2.z *= d2; a2.w *= d2;
        sth4(&Hout16[(size_t)(r0 + 2) * HID + c4], a2); }
    if (r0 + 3 < N_NODES) { float d3 = dinv[r0 + 3];
        a3.x *= d3; a3.y *= d3; a3.z *= d3; a3.w *= d3;
        sth4(&Hout16[(size_t)(r0 + 3) * HID + c4], a3); }
}

// ---- fused: gather L2 (pre-scaled) -> relu -> fp16 LDS -> run-length pool ----
__global__ __launch_bounds__(256) void k_gatherpool(const __half* __restrict__ hw16,
                                                    const int* __restrict__ eidx,
                                                    const int* __restrict__ rowptr,
                                                    const float* __restrict__ dinv,
                                                    const float* __restrict__ bias,
                                                    const int* __restrict__ batch,
                                                    float* __restrict__ gsum) {
    __shared__ __half Xl[64][72];      // 9 KB fp16
    __shared__ int bl[64];
    const int tid  = threadIdx.x;
    const int ng4  = tid >> 4;
    const int tile = blockIdx.x;
    const int c4   = (tid & 15) * 4;

    if (tid < 64) {
        int node = tile * 64 + tid;
        bl[tid] = (node < N_NODES) ? batch[node] : -1;
    }

    float4 b = *(const float4*)&bias[c4];
    #pragma unroll
    for (int j = 0; j < 4; ++j) {
        int node = tile * 64 + ng4 * 4 + j;
        float4 r = make_float4(0.f, 0.f, 0.f, 0.f);
        if (node < N_NODES) {
            int e0 = rowptr[node], e1 = rowptr[node + 1];
            float4 acc = gather_row_nw(hw16, eidx, e0, e1, c4);
            float di = dinv[node];
            float4 hw = ldh4(&hw16[(size_t)node * HID + c4]);
            r.x = fmaxf(fmaf(di, acc.x + hw.x, b.x), 0.f);
            r.y = fmaxf(fmaf(di, acc.y + hw.y, b.y), 0.f);
            r.z = fmaxf(fmaf(di, acc.z + hw.z, b.z), 0.f);
            r.w = fmaxf(fmaf(di, acc.w + hw.w, b.w), 0.f);
        }
        sth4(&Xl[ng4 * 4 + j][c4], r);
    }
    __syncthreads();

    if (tid < 64) {
        int c = tid;
        float acc = 0.f;
        int gprev = bl[0];
        #pragma unroll 8
        for (int n = 0; n < 64; ++n) {
            int g = bl[n];
            if (g < 0) break;
            if (g != gprev) {
                unsafeAtomicAdd(&gsum[gprev * HID + c], acc);
                acc = 0.f;
                gprev = g;
            }
            acc += __half2float(Xl[n][c]);
        }
        if (gprev >= 0) unsafeAtomicAdd(&gsum[gprev * HID + c], acc);
    }
}

__global__ void k_out(const float* __restrict__ gsum, const int* __restrict__ gcnt,
                      const float* __restrict__ Wout, const float* __restrict__ bout,
                      float* __restrict__ out) {
    int g = threadIdx.x;
    if (g >= NG) return;
    float acc = 0.f;
    for (int c = 0; c < HID; ++c) acc += gsum[g * HID + c] * Wout[c];
    float cnt = fmaxf((float)gcnt[g], 1.0f);
    out[g] = acc / cnt + bout[0];
}

extern "C" void kernel_launch(void* const* d_in, const int* in_sizes, int n_in,
                              void* d_out, int out_size, void* d_ws, size_t ws_size,
                              hipStream_t stream) {
    const float* x    = (const float*)d_in[0];
    const int*   ei   = (const int*)d_in[1];
    const int*   batch= (const int*)d_in[2];
    const float* W1   = (const float*)d_in[3];
    const float* b1   = (const float*)d_in[4];
    const float* W2   = (const float*)d_in[5];
    const float* b2   = (const float*)d_in[6];
    const float* Wout = (const float*)d_in[7];
    const float* bout = (const float*)d_in[8];
    float* out = (float*)d_out;

    const int* src  = ei;
    const int* dstp = ei + N_EDGES;

    char* w = (char*)d_ws;
    int*    hist  = (int*)w;    w += (size_t)NBINS * NBLK * 4;
    int*    bstrt = (int*)w;    w += (size_t)(NBINS + 8) * 4;
    int*    gcnt  = (int*)w;    w += (size_t)NG * 4;
    int*    bsum  = (int*)w;    w += (size_t)512 * 4;
    int*    boff  = (int*)w;    w += (size_t)512 * 4;
    int*    rowptr= (int*)w;    w += (size_t)(N_NODES + 4) * 4;
    float*  dinv  = (float*)w;  w += (size_t)N_NODES * 4;
    float*  gsum  = (float*)w;  w += (size_t)NG * HID * 4;
    int*    eidx  = (int*)w;    w += (size_t)N_EDGES * 4;
    __half* bufA16= (__half*)w; w += (size_t)N_NODES * HID * 2;
    __half* bufB16= (__half*)w; w += (size_t)N_NODES * HID * 2;

    hipMemsetAsync(gcnt, 0, (size_t)NG * 4, stream);
    hipMemsetAsync(gsum, 0, (size_t)NG * HID * 4, stream);

    // fused: gemm1 || LDS bucket-count || batch counts  (zero global atomic-returns)
    k_front<<<GEMB + NBLK + CNTB, 256, 0, stream>>>(dstp, hist, batch, gcnt,
                                                    x, W1, bufA16);
    // linear exclusive scan of hist
    k_bsum   <<<NBLK, 1024, 0, stream>>>(hist, bsum);
    k_scanb  <<<1, 512, 0, stream>>>(bsum, boff, NBLK);
    k_scanfin<<<NBLK, 1024, 0, stream>>>(hist, boff, bstrt);
    // bucket-grouped scatter (LDS atomic-returns only)
    k_scatter<<<NBLK, 256, 0, stream>>>(src, dstp, hist, eidx);
    // per-bucket CSR finalize
    k_bucketcsr<<<BUCKETS, 256, 0, stream>>>(eidx, bstrt, rowptr, dinv);

    // Layer-1 aggregation fused with layer-2 GEMM (writes pre-scaled fp16)
    k_gathergemm<<<GEMB, 256, 0, stream>>>(bufA16, eidx, rowptr, dinv, b1, W2, bufB16);
    // Layer-2 aggregation fused with mean-pool partials
    k_gatherpool<<<GEMB, 256, 0, stream>>>(bufB16, eidx, rowptr, dinv, b2, batch, gsum);

    k_out<<<1, 128, 0, stream>>>(gsum, gcnt, Wout, bout, out);
}

// Round 15
// 225.585 us; speedup vs baseline: 1.0800x; 1.0800x over previous
//
#include <hip/hip_runtime.h>
#include <hip/hip_fp16.h>

#define N_NODES 100000
#define N_EDGES 1600000
#define F_IN 128
#define HID 64
#define NG 128

#define GEMB 1563    // 64-row gemm tiles
#define NBINS 1024   // buckets = dst>>7 (782 used)
#define NBLK  391    // pass-A blocks, 4096 edges each
#define BUCKETS 782  // ceil(100000/128)
#define CNTB 391

#define FMA_ROW(acc, xv) \
    acc.x = fmaf(xv.x, w0.x, acc.x); acc.y = fmaf(xv.x, w0.y, acc.y); \
    acc.z = fmaf(xv.x, w0.z, acc.z); acc.w = fmaf(xv.x, w0.w, acc.w); \
    acc.x = fmaf(xv.y, w1.x, acc.x); acc.y = fmaf(xv.y, w1.y, acc.y); \
    acc.z = fmaf(xv.y, w1.z, acc.z); acc.w = fmaf(xv.y, w1.w, acc.w); \
    acc.x = fmaf(xv.z, w2.x, acc.x); acc.y = fmaf(xv.z, w2.y, acc.y); \
    acc.z = fmaf(xv.z, w2.z, acc.z); acc.w = fmaf(xv.z, w2.w, acc.w); \
    acc.x = fmaf(xv.w, w3.x, acc.x); acc.y = fmaf(xv.w, w3.y, acc.y); \
    acc.z = fmaf(xv.w, w3.z, acc.z); acc.w = fmaf(xv.w, w3.w, acc.w);

#define FMA_EDGE(hh, ww) \
    acc.x = fmaf(hh.x, ww, acc.x); acc.y = fmaf(hh.y, ww, acc.y); \
    acc.z = fmaf(hh.z, ww, acc.z); acc.w = fmaf(hh.w, ww, acc.w);

#define ADD_EDGE(hh) \
    acc.x += hh.x; acc.y += hh.y; acc.z += hh.z; acc.w += hh.w;

__device__ __forceinline__ float4 ldh4(const __half* p) {
    uint2 u = *(const uint2*)p;
    __half2 a = *(__half2*)&u.x, b = *(__half2*)&u.y;
    float2 fa = __half22float2(a), fb = __half22float2(b);
    return make_float4(fa.x, fa.y, fb.x, fb.y);
}
__device__ __forceinline__ void sth4(__half* p, float4 v) {
    __half2 a = __floats2half2_rn(v.x, v.y), b = __floats2half2_rn(v.z, v.w);
    uint2 u; u.x = *(unsigned int*)&a; u.y = *(unsigned int*)&b;
    *(uint2*)p = u;
}

__device__ __forceinline__ float4 gather_row_w(const __half* __restrict__ h16,
                                               const int* __restrict__ eidx,
                                               const float* __restrict__ dinv,
                                               int e0, int e1, int c4) {
    float4 acc = make_float4(0.f, 0.f, 0.f, 0.f);
    int e = e0;
    for (; e + 7 < e1; e += 8) {
        int s0 = eidx[e],     s1 = eidx[e + 1], s2 = eidx[e + 2], s3 = eidx[e + 3];
        int s4 = eidx[e + 4], s5 = eidx[e + 5], s6 = eidx[e + 6], s7 = eidx[e + 7];
        float w0 = dinv[s0], w1 = dinv[s1], w2 = dinv[s2], w3 = dinv[s3];
        float w4 = dinv[s4], w5 = dinv[s5], w6 = dinv[s6], w7 = dinv[s7];
        float4 h0 = ldh4(&h16[(size_t)s0 * HID + c4]);
        float4 h1 = ldh4(&h16[(size_t)s1 * HID + c4]);
        float4 h2 = ldh4(&h16[(size_t)s2 * HID + c4]);
        float4 h3 = ldh4(&h16[(size_t)s3 * HID + c4]);
        float4 h4 = ldh4(&h16[(size_t)s4 * HID + c4]);
        float4 h5 = ldh4(&h16[(size_t)s5 * HID + c4]);
        float4 h6 = ldh4(&h16[(size_t)s6 * HID + c4]);
        float4 h7 = ldh4(&h16[(size_t)s7 * HID + c4]);
        FMA_EDGE(h0, w0); FMA_EDGE(h1, w1); FMA_EDGE(h2, w2); FMA_EDGE(h3, w3);
        FMA_EDGE(h4, w4); FMA_EDGE(h5, w5); FMA_EDGE(h6, w6); FMA_EDGE(h7, w7);
    }
    if (e + 3 < e1) {
        int s0 = eidx[e], s1 = eidx[e + 1], s2 = eidx[e + 2], s3 = eidx[e + 3];
        float w0 = dinv[s0], w1 = dinv[s1], w2 = dinv[s2], w3 = dinv[s3];
        float4 h0 = ldh4(&h16[(size_t)s0 * HID + c4]);
        float4 h1 = ldh4(&h16[(size_t)s1 * HID + c4]);
        float4 h2 = ldh4(&h16[(size_t)s2 * HID + c4]);
        float4 h3 = ldh4(&h16[(size_t)s3 * HID + c4]);
        FMA_EDGE(h0, w0); FMA_EDGE(h1, w1); FMA_EDGE(h2, w2); FMA_EDGE(h3, w3);
        e += 4;
    }
    for (; e < e1; ++e) {
        int s0 = eidx[e];
        float w0 = dinv[s0];
        float4 h0 = ldh4(&h16[(size_t)s0 * HID + c4]);
        FMA_EDGE(h0, w0);
    }
    return acc;
}

__device__ __forceinline__ float4 gather_row_nw(const __half* __restrict__ h16,
                                                const int* __restrict__ eidx,
                                                int e0, int e1, int c4) {
    float4 acc = make_float4(0.f, 0.f, 0.f, 0.f);
    int e = e0;
    for (; e + 7 < e1; e += 8) {
        int s0 = eidx[e],     s1 = eidx[e + 1], s2 = eidx[e + 2], s3 = eidx[e + 3];
        int s4 = eidx[e + 4], s5 = eidx[e + 5], s6 = eidx[e + 6], s7 = eidx[e + 7];
        float4 h0 = ldh4(&h16[(size_t)s0 * HID + c4]);
        float4 h1 = ldh4(&h16[(size_t)s1 * HID + c4]);
        float4 h2 = ldh4(&h16[(size_t)s2 * HID + c4]);
        float4 h3 = ldh4(&h16[(size_t)s3 * HID + c4]);
        float4 h4 = ldh4(&h16[(size_t)s4 * HID + c4]);
        float4 h5 = ldh4(&h16[(size_t)s5 * HID + c4]);
        float4 h6 = ldh4(&h16[(size_t)s6 * HID + c4]);
        float4 h7 = ldh4(&h16[(size_t)s7 * HID + c4]);
        ADD_EDGE(h0); ADD_EDGE(h1); ADD_EDGE(h2); ADD_EDGE(h3);
        ADD_EDGE(h4); ADD_EDGE(h5); ADD_EDGE(h6); ADD_EDGE(h7);
    }
    if (e + 3 < e1) {
        int s0 = eidx[e], s1 = eidx[e + 1], s2 = eidx[e + 2], s3 = eidx[e + 3];
        float4 h0 = ldh4(&h16[(size_t)s0 * HID + c4]);
        float4 h1 = ldh4(&h16[(size_t)s1 * HID + c4]);
        float4 h2 = ldh4(&h16[(size_t)s2 * HID + c4]);
        float4 h3 = ldh4(&h16[(size_t)s3 * HID + c4]);
        ADD_EDGE(h0); ADD_EDGE(h1); ADD_EDGE(h2); ADD_EDGE(h3);
        e += 4;
    }
    for (; e < e1; ++e) {
        int s0 = eidx[e];
        float4 h0 = ldh4(&h16[(size_t)s0 * HID + c4]);
        ADD_EDGE(h0);
    }
    return acc;
}

template <int K>
__device__ __forceinline__ void gemm_tile(const float* __restrict__ X,
                                          const float* __restrict__ W,
                                          __half* __restrict__ H16,
                                          int tile, float* smem) {
    const int tid = threadIdx.x;
    const int rg  = tid >> 4;
    const int c4  = (tid & 15) * 4;
    const int r0  = tile * 64 + rg * 4;
    const bool full = (r0 + 3 < N_NODES);

    float4 a0 = {0,0,0,0}, a1 = {0,0,0,0}, a2 = {0,0,0,0}, a3 = {0,0,0,0};

    for (int kh = 0; kh < K; kh += 64) {
        __syncthreads();
        for (int i = tid; i < 1024; i += 256)
            ((float4*)smem)[i] = ((const float4*)(W + kh * 64))[i];
        __syncthreads();

        const float* Xb = X + (size_t)r0 * K + kh;
        #pragma unroll 4
        for (int k2 = 0; k2 < 64; k2 += 4) {
            float4 w0 = *(float4*)&smem[(k2 + 0) * 64 + c4];
            float4 w1 = *(float4*)&smem[(k2 + 1) * 64 + c4];
            float4 w2 = *(float4*)&smem[(k2 + 2) * 64 + c4];
            float4 w3 = *(float4*)&smem[(k2 + 3) * 64 + c4];
            float4 x0 = {0,0,0,0}, x1 = {0,0,0,0}, x2 = {0,0,0,0}, x3 = {0,0,0,0};
            if (full) {
                x0 = *(const float4*)&Xb[0 * (size_t)K + k2];
                x1 = *(const float4*)&Xb[1 * (size_t)K + k2];
                x2 = *(const float4*)&Xb[2 * (size_t)K + k2];
                x3 = *(const float4*)&Xb[3 * (size_t)K + k2];
            } else {
                if (r0 + 0 < N_NODES) x0 = *(const float4*)&Xb[0 * (size_t)K + k2];
                if (r0 + 1 < N_NODES) x1 = *(const float4*)&Xb[1 * (size_t)K + k2];
                if (r0 + 2 < N_NODES) x2 = *(const float4*)&Xb[2 * (size_t)K + k2];
                if (r0 + 3 < N_NODES) x3 = *(const float4*)&Xb[3 * (size_t)K + k2];
            }
            FMA_ROW(a0, x0);
            FMA_ROW(a1, x1);
            FMA_ROW(a2, x2);
            FMA_ROW(a3, x3);
        }
    }

    if (full) {
        sth4(&H16[(size_t)(r0 + 0) * HID + c4], a0);
        sth4(&H16[(size_t)(r0 + 1) * HID + c4], a1);
        sth4(&H16[(size_t)(r0 + 2) * HID + c4], a2);
        sth4(&H16[(size_t)(r0 + 3) * HID + c4], a3);
    } else {
        if (r0 + 0 < N_NODES) sth4(&H16[(size_t)(r0 + 0) * HID + c4], a0);
        if (r0 + 1 < N_NODES) sth4(&H16[(size_t)(r0 + 1) * HID + c4], a1);
        if (r0 + 2 < N_NODES) sth4(&H16[(size_t)(r0 + 2) * HID + c4], a2);
        if (r0 + 3 < N_NODES) sth4(&H16[(size_t)(r0 + 3) * HID + c4], a3);
    }
}

// ---- fused front: [gemm1 | LDS bucket-count (no global atomics) | batch counts] ----
__global__ __launch_bounds__(256) void k_front(const int* __restrict__ dst,
                                               int* __restrict__ hist,   // [NBINS][NBLK]
                                               const int* __restrict__ batch,
                                               int* __restrict__ gcnt,
                                               const float* __restrict__ X,
                                               const float* __restrict__ W,
                                               __half* __restrict__ H16) {
    __shared__ float smem[4096];   // 16 KB
    int bid = blockIdx.x;
    int tid = threadIdx.x;
    if (bid < GEMB) {
        gemm_tile<F_IN>(X, W, H16, bid, smem);
    } else if (bid < GEMB + NBLK) {
        int cb = bid - GEMB;
        int* bins = (int*)smem;
        for (int i = tid; i < NBINS; i += 256) bins[i] = 0;
        __syncthreads();
        #pragma unroll
        for (int it = 0; it < 4; ++it) {
            int base = cb * 4096 + it * 1024 + tid * 4;
            if (base < N_EDGES) {
                int4 d4 = *(const int4*)&dst[base];
                atomicAdd(&bins[d4.x >> 7], 1);
                atomicAdd(&bins[d4.y >> 7], 1);
                atomicAdd(&bins[d4.z >> 7], 1);
                atomicAdd(&bins[d4.w >> 7], 1);
            }
        }
        __syncthreads();
        for (int i = tid; i < NBINS; i += 256) hist[(size_t)i * NBLK + cb] = bins[i];
    } else {
        int* bins = (int*)smem;
        if (tid < NG) bins[tid] = 0;
        __syncthreads();
        int i = (bid - GEMB - NBLK) * 256 + tid;
        if (i < N_NODES) atomicAdd(&bins[batch[i]], 1);
        __syncthreads();
        if (tid < NG && bins[tid] != 0) atomicAdd(&gcnt[tid], bins[tid]);
    }
}

// ---- scan L1: 391 blocks x 1024 over hist (400384 = 391*1024 exactly) ----
__global__ __launch_bounds__(1024) void k_bsum(const int* __restrict__ hist,
                                               int* __restrict__ bsum) {
    __shared__ int red[1024];
    int i = blockIdx.x * 1024 + threadIdx.x;
    red[threadIdx.x] = hist[i];
    __syncthreads();
    for (int off = 512; off > 0; off >>= 1) {
        if (threadIdx.x < off) red[threadIdx.x] += red[threadIdx.x + off];
        __syncthreads();
    }
    if (threadIdx.x == 0) bsum[blockIdx.x] = red[0];
}

__global__ __launch_bounds__(512) void k_scanb(const int* __restrict__ bsum,
                                               int* __restrict__ boff, int nb) {
    __shared__ int tmp[512];
    int t = threadIdx.x;
    int v = (t < nb) ? bsum[t] : 0;
    tmp[t] = v;
    __syncthreads();
    for (int off = 1; off < 512; off <<= 1) {
        int u = (t >= off) ? tmp[t - off] : 0;
        __syncthreads();
        tmp[t] += u;
        __syncthreads();
    }
    if (t < nb) boff[t] = tmp[t] - v;
}

// ---- scan L3: in-place exclusive scan of hist; emit bucketstart ----
__global__ __launch_bounds__(1024) void k_scanfin(int* __restrict__ hist,
                                                  const int* __restrict__ boff,
                                                  int* __restrict__ bucketstart) {
    __shared__ int tmp[1024];
    int i = blockIdx.x * 1024 + threadIdx.x;
    int t = threadIdx.x;
    int v = hist[i];
    tmp[t] = v;
    __syncthreads();
    for (int off = 1; off < 1024; off <<= 1) {
        int u = (t >= off) ? tmp[t - off] : 0;
        __syncthreads();
        tmp[t] += u;
        __syncthreads();
    }
    int excl = boff[blockIdx.x] + tmp[t] - v;
    hist[i] = excl;
    if (i % NBLK == 0) bucketstart[i / NBLK] = excl;   // i = bin*NBLK
}

// ---- scatter: LDS cursors (atomic-return in LDS only) -> bucket-grouped recs ----
__global__ __launch_bounds__(256) void k_scatter(const int* __restrict__ src,
                                                 const int* __restrict__ dst,
                                                 const int* __restrict__ hist,
                                                 int* __restrict__ ebuf) {
    __shared__ int cur[NBINS];
    int cb = blockIdx.x;
    int tid = threadIdx.x;
    for (int i = tid; i < NBINS; i += 256) cur[i] = hist[(size_t)i * NBLK + cb];
    __syncthreads();
    #pragma unroll
    for (int it = 0; it < 4; ++it) {
        int base = cb * 4096 + it * 1024 + tid * 4;
        if (base < N_EDGES) {
            int4 s4 = *(const int4*)&src[base];
            int4 d4 = *(const int4*)&dst[base];
            int p0 = atomicAdd(&cur[d4.x >> 7], 1);
            int p1 = atomicAdd(&cur[d4.y >> 7], 1);
            int p2 = atomicAdd(&cur[d4.z >> 7], 1);
            int p3 = atomicAdd(&cur[d4.w >> 7], 1);
            ebuf[p0] = (s4.x << 7) | (d4.x & 127);
            ebuf[p1] = (s4.y << 7) | (d4.y & 127);
            ebuf[p2] = (s4.z << 7) | (d4.z & 127);
            ebuf[p3] = (s4.w << 7) | (d4.w & 127);
        }
    }
}

// ---- per-bucket CSR: stage recs in LDS, count/scan 128 nodes, place in-place ----
__global__ __launch_bounds__(256) void k_bucketcsr(int* __restrict__ eidx,   // = ebuf
                                                   const int* __restrict__ bucketstart,
                                                   int* __restrict__ rowptr,
                                                   float* __restrict__ dinv) {
    __shared__ int lrec[4096];
    __shared__ int lcnt[128];
    __shared__ int lsum[128];
    __shared__ int lcur[128];
    int b = blockIdx.x;
    int tid = threadIdx.x;
    int s0 = bucketstart[b], s1 = bucketstart[b + 1];
    int cnt = s1 - s0;

    if (tid < 128) lcnt[tid] = 0;
    __syncthreads();
    for (int i = tid; i < cnt; i += 256) {
        int r = eidx[s0 + i];
        lrec[i] = r;
        atomicAdd(&lcnt[r & 127], 1);
    }
    __syncthreads();
    if (tid < 128) lsum[tid] = lcnt[tid];
    __syncthreads();
    for (int off = 1; off < 128; off <<= 1) {
        int u = 0;
        if (tid < 128 && tid >= off) u = lsum[tid - off];
        __syncthreads();
        if (tid < 128) lsum[tid] += u;
        __syncthreads();
    }
    if (tid < 128) {
        int excl = lsum[tid] - lcnt[tid];
        lcur[tid] = s0 + excl;
        int node = b * 128 + tid;
        if (node < N_NODES) {
            rowptr[node] = s0 + excl;
            dinv[node] = 1.0f / sqrtf((float)lcnt[tid] + 1.0f);
        }
    }
    __syncthreads();
    for (int i = tid; i < cnt; i += 256) {
        int r = lrec[i];
        int p = atomicAdd(&lcur[r & 127], 1);
        eidx[p] = r >> 7;
    }
    if (b == 0 && tid == 0) rowptr[N_NODES] = N_EDGES;
}

// ---- fused: gather L1 -> relu -> fp32 LDS -> gemm x W2 (global/L1) -> pre-scaled fp16 ----
// No W LDS stage: W2 (16KB) is L1-resident; LDS 33->17KB doubles occupancy (R13/R14 lesson:
// keep VGPR <= 64, no cvt on hot path)
__global__ __launch_bounds__(256) void k_gathergemm(const __half* __restrict__ h16,
                                                    const int* __restrict__ eidx,
                                                    const int* __restrict__ rowptr,
                                                    const float* __restrict__ dinv,
                                                    const float* __restrict__ bias,
                                                    const float* __restrict__ W2,
                                                    __half* __restrict__ Hout16) {
    __shared__ float Xl[64][66];
    const int tid  = threadIdx.x;
    const int ng4  = tid >> 4;
    const int tile = blockIdx.x;
    const int c4   = (tid & 15) * 4;

    float4 b = *(const float4*)&bias[c4];
    #pragma unroll
    for (int j = 0; j < 4; ++j) {
        int node = tile * 64 + ng4 * 4 + j;
        float4 r = make_float4(0.f, 0.f, 0.f, 0.f);
        if (node < N_NODES) {
            int e0 = rowptr[node], e1 = rowptr[node + 1];
            float4 acc = gather_row_w(h16, eidx, dinv, e0, e1, c4);
            float di = dinv[node];
            float4 hd = ldh4(&h16[(size_t)node * HID + c4]);
            r.x = fmaxf(fmaf(di, fmaf(di, hd.x, acc.x), b.x), 0.f);
            r.y = fmaxf(fmaf(di, fmaf(di, hd.y, acc.y), b.y), 0.f);
            r.z = fmaxf(fmaf(di, fmaf(di, hd.z, acc.z), b.z), 0.f);
            r.w = fmaxf(fmaf(di, fmaf(di, hd.w, acc.w), b.w), 0.f);
        }
        *(float4*)&Xl[ng4 * 4 + j][c4] = r;
    }
    __syncthreads();

    float4 a0 = {0,0,0,0}, a1 = {0,0,0,0}, a2 = {0,0,0,0}, a3 = {0,0,0,0};
    #pragma unroll 4
    for (int k2 = 0; k2 < 64; k2 += 4) {
        float4 w0 = *(const float4*)&W2[(k2 + 0) * 64 + c4];
        float4 w1 = *(const float4*)&W2[(k2 + 1) * 64 + c4];
        float4 w2 = *(const float4*)&W2[(k2 + 2) * 64 + c4];
        float4 w3 = *(const float4*)&W2[(k2 + 3) * 64 + c4];
        float4 x0 = *(float4*)&Xl[ng4 * 4 + 0][k2];
        float4 x1 = *(float4*)&Xl[ng4 * 4 + 1][k2];
        float4 x2 = *(float4*)&Xl[ng4 * 4 + 2][k2];
        float4 x3 = *(float4*)&Xl[ng4 * 4 + 3][k2];
        FMA_ROW(a0, x0);
        FMA_ROW(a1, x1);
        FMA_ROW(a2, x2);
        FMA_ROW(a3, x3);
    }

    const int r0 = tile * 64 + ng4 * 4;
    if (r0 + 0 < N_NODES) { float d0 = dinv[r0 + 0];
        a0.x *= d0; a0.y *= d0; a0.z *= d0; a0.w *= d0;
        sth4(&Hout16[(size_t)(r0 + 0) * HID + c4], a0); }
    if (r0 + 1 < N_NODES) { float d1 = dinv[r0 + 1];
        a1.x *= d1; a1.y *= d1; a1.z *= d1; a1.w *= d1;
        sth4(&Hout16[(size_t)(r0 + 1) * HID + c4], a1); }
    if (r0 + 2 < N_NODES) { float d2 = dinv[r0 + 2];
        a2.x *= d2; a2.y *= d2; a2.z *= d2; a2.w *= d2;
        sth4(&Hout16[(size_t)(r0 + 2) * HID + c4], a2); }
    if (r0 + 3 < N_NODES) { float d3 = dinv[r0 + 3];
        a3.x *= d3; a3.y *= d3; a3.z *= d3; a3.w *= d3;
        sth4(&Hout16[(size_t)(r0 + 3) * HID + c4], a3); }
}

// ---- fused: gather L2 (pre-scaled) -> relu -> fp32 LDS -> run-length pool ----
__global__ __launch_bounds__(256) void k_gatherpool(const __half* __restrict__ hw16,
                                                    const int* __restrict__ eidx,
                                                    const int* __restrict__ rowptr,
                                                    const float* __restrict__ dinv,
                                                    const float* __restrict__ bias,
                                                    const int* __restrict__ batch,
                                                    float* __restrict__ gsum) {
    __shared__ float Xl[64][66];
    __shared__ int bl[64];
    const int tid  = threadIdx.x;
    const int ng4  = tid >> 4;
    const int tile = blockIdx.x;
    const int c4   = (tid & 15) * 4;

    if (tid < 64) {
        int node = tile * 64 + tid;
        bl[tid] = (node < N_NODES) ? batch[node] : -1;
    }

    float4 b = *(const float4*)&bias[c4];
    #pragma unroll
    for (int j = 0; j < 4; ++j) {
        int node = tile * 64 + ng4 * 4 + j;
        float4 r = make_float4(0.f, 0.f, 0.f, 0.f);
        if (node < N_NODES) {
            int e0 = rowptr[node], e1 = rowptr[node + 1];
            float4 acc = gather_row_nw(hw16, eidx, e0, e1, c4);
            float di = dinv[node];
            float4 hw = ldh4(&hw16[(size_t)node * HID + c4]);
            r.x = fmaxf(fmaf(di, acc.x + hw.x, b.x), 0.f);
            r.y = fmaxf(fmaf(di, acc.y + hw.y, b.y), 0.f);
            r.z = fmaxf(fmaf(di, acc.z + hw.z, b.z), 0.f);
            r.w = fmaxf(fmaf(di, acc.w + hw.w, b.w), 0.f);
        }
        *(float4*)&Xl[ng4 * 4 + j][c4] = r;
    }
    __syncthreads();

    if (tid < 64) {
        int c = tid;
        float acc = 0.f;
        int gprev = bl[0];
        #pragma unroll 8
        for (int n = 0; n < 64; ++n) {
            int g = bl[n];
            if (g < 0) break;
            if (g != gprev) {
                unsafeAtomicAdd(&gsum[gprev * HID + c], acc);
                acc = 0.f;
                gprev = g;
            }
            acc += Xl[n][c];
        }
        if (gprev >= 0) unsafeAtomicAdd(&gsum[gprev * HID + c], acc);
    }
}

__global__ void k_out(const float* __restrict__ gsum, const int* __restrict__ gcnt,
                      const float* __restrict__ Wout, const float* __restrict__ bout,
                      float* __restrict__ out) {
    int g = threadIdx.x;
    if (g >= NG) return;
    float acc = 0.f;
    for (int c = 0; c < HID; ++c) acc += gsum[g * HID + c] * Wout[c];
    float cnt = fmaxf((float)gcnt[g], 1.0f);
    out[g] = acc / cnt + bout[0];
}

extern "C" void kernel_launch(void* const* d_in, const int* in_sizes, int n_in,
                              void* d_out, int out_size, void* d_ws, size_t ws_size,
                              hipStream_t stream) {
    const float* x    = (const float*)d_in[0];
    const int*   ei   = (const int*)d_in[1];
    const int*   batch= (const int*)d_in[2];
    const float* W1   = (const float*)d_in[3];
    const float* b1   = (const float*)d_in[4];
    const float* W2   = (const float*)d_in[5];
    const float* b2   = (const float*)d_in[6];
    const float* Wout = (const float*)d_in[7];
    const float* bout = (const float*)d_in[8];
    float* out = (float*)d_out;

    const int* src  = ei;
    const int* dstp = ei + N_EDGES;

    char* w = (char*)d_ws;
    int*    hist  = (int*)w;    w += (size_t)NBINS * NBLK * 4;
    int*    bstrt = (int*)w;    w += (size_t)(NBINS + 8) * 4;
    int*    gcnt  = (int*)w;    w += (size_t)NG * 4;
    int*    bsum  = (int*)w;    w += (size_t)512 * 4;
    int*    boff  = (int*)w;    w += (size_t)512 * 4;
    int*    rowptr= (int*)w;    w += (size_t)(N_NODES + 4) * 4;
    float*  dinv  = (float*)w;  w += (size_t)N_NODES * 4;
    float*  gsum  = (float*)w;  w += (size_t)NG * HID * 4;
    int*    eidx  = (int*)w;    w += (size_t)N_EDGES * 4;
    __half* bufA16= (__half*)w; w += (size_t)N_NODES * HID * 2;
    __half* bufB16= (__half*)w; w += (size_t)N_NODES * HID * 2;

    hipMemsetAsync(gcnt, 0, (size_t)NG * 4, stream);
    hipMemsetAsync(gsum, 0, (size_t)NG * HID * 4, stream);

    // fused: gemm1 || LDS bucket-count || batch counts  (zero global atomic-returns)
    k_front<<<GEMB + NBLK + CNTB, 256, 0, stream>>>(dstp, hist, batch, gcnt,
                                                    x, W1, bufA16);
    // linear exclusive scan of hist
    k_bsum   <<<NBLK, 1024, 0, stream>>>(hist, bsum);
    k_scanb  <<<1, 512, 0, stream>>>(bsum, boff, NBLK);
    k_scanfin<<<NBLK, 1024, 0, stream>>>(hist, boff, bstrt);
    // bucket-grouped scatter (LDS atomic-returns only)
    k_scatter<<<NBLK, 256, 0, stream>>>(src, dstp, hist, eidx);
    // per-bucket CSR finalize
    k_bucketcsr<<<BUCKETS, 256, 0, stream>>>(eidx, bstrt, rowptr, dinv);

    // Layer-1 aggregation fused with layer-2 GEMM (writes pre-scaled fp16)
    k_gathergemm<<<GEMB, 256, 0, stream>>>(bufA16, eidx, rowptr, dinv, b1, W2, bufB16);
    // Layer-2 aggregation fused with mean-pool partials
    k_gatherpool<<<GEMB, 256, 0, stream>>>(bufB16, eidx, rowptr, dinv, b2, batch, gsum);

    k_out<<<1, 128, 0, stream>>>(gsum, gcnt, Wout, bout, out);
}

// Round 16
// 221.680 us; speedup vs baseline: 1.0990x; 1.0176x over previous
//
#include <hip/hip_runtime.h>
#include <hip/hip_fp16.h>

#define N_NODES 100000
#define N_EDGES 1600000
#define F_IN 128
#define HID 64
#define NG 128

#define GEMB 1563    // 64-row gemm tiles
#define NBINS 1024   // buckets = dst>>7 (782 used)
#define NBLK  391    // hist/scatter blocks, 4096 edges each
#define BUCKETS 782  // ceil(100000/128)
#define CNTB 391

#define FMA_ROW(acc, xv) \
    acc.x = fmaf(xv.x, w0.x, acc.x); acc.y = fmaf(xv.x, w0.y, acc.y); \
    acc.z = fmaf(xv.x, w0.z, acc.z); acc.w = fmaf(xv.x, w0.w, acc.w); \
    acc.x = fmaf(xv.y, w1.x, acc.x); acc.y = fmaf(xv.y, w1.y, acc.y); \
    acc.z = fmaf(xv.y, w1.z, acc.z); acc.w = fmaf(xv.y, w1.w, acc.w); \
    acc.x = fmaf(xv.z, w2.x, acc.x); acc.y = fmaf(xv.z, w2.y, acc.y); \
    acc.z = fmaf(xv.z, w2.z, acc.z); acc.w = fmaf(xv.z, w2.w, acc.w); \
    acc.x = fmaf(xv.w, w3.x, acc.x); acc.y = fmaf(xv.w, w3.y, acc.y); \
    acc.z = fmaf(xv.w, w3.z, acc.z); acc.w = fmaf(xv.w, w3.w, acc.w);

#define FMA_EDGE(hh, ww) \
    acc.x = fmaf(hh.x, ww, acc.x); acc.y = fmaf(hh.y, ww, acc.y); \
    acc.z = fmaf(hh.z, ww, acc.z); acc.w = fmaf(hh.w, ww, acc.w);

#define ADD_EDGE(hh) \
    acc.x += hh.x; acc.y += hh.y; acc.z += hh.z; acc.w += hh.w;

__device__ __forceinline__ float4 ldh4(const __half* p) {
    uint2 u = *(const uint2*)p;
    __half2 a = *(__half2*)&u.x, b = *(__half2*)&u.y;
    float2 fa = __half22float2(a), fb = __half22float2(b);
    return make_float4(fa.x, fa.y, fb.x, fb.y);
}
__device__ __forceinline__ void sth4(__half* p, float4 v) {
    __half2 a = __floats2half2_rn(v.x, v.y), b = __floats2half2_rn(v.z, v.w);
    uint2 u; u.x = *(unsigned int*)&a; u.y = *(unsigned int*)&b;
    *(uint2*)p = u;
}

__device__ __forceinline__ float4 gather_row_w(const __half* __restrict__ h16,
                                               const int* __restrict__ eidx,
                                               const float* __restrict__ dinv,
                                               int e0, int e1, int c4) {
    float4 acc = make_float4(0.f, 0.f, 0.f, 0.f);
    int e = e0;
    for (; e + 7 < e1; e += 8) {
        int s0 = eidx[e],     s1 = eidx[e + 1], s2 = eidx[e + 2], s3 = eidx[e + 3];
        int s4 = eidx[e + 4], s5 = eidx[e + 5], s6 = eidx[e + 6], s7 = eidx[e + 7];
        float w0 = dinv[s0], w1 = dinv[s1], w2 = dinv[s2], w3 = dinv[s3];
        float w4 = dinv[s4], w5 = dinv[s5], w6 = dinv[s6], w7 = dinv[s7];
        float4 h0 = ldh4(&h16[(size_t)s0 * HID + c4]);
        float4 h1 = ldh4(&h16[(size_t)s1 * HID + c4]);
        float4 h2 = ldh4(&h16[(size_t)s2 * HID + c4]);
        float4 h3 = ldh4(&h16[(size_t)s3 * HID + c4]);
        float4 h4 = ldh4(&h16[(size_t)s4 * HID + c4]);
        float4 h5 = ldh4(&h16[(size_t)s5 * HID + c4]);
        float4 h6 = ldh4(&h16[(size_t)s6 * HID + c4]);
        float4 h7 = ldh4(&h16[(size_t)s7 * HID + c4]);
        FMA_EDGE(h0, w0); FMA_EDGE(h1, w1); FMA_EDGE(h2, w2); FMA_EDGE(h3, w3);
        FMA_EDGE(h4, w4); FMA_EDGE(h5, w5); FMA_EDGE(h6, w6); FMA_EDGE(h7, w7);
    }
    if (e + 3 < e1) {
        int s0 = eidx[e], s1 = eidx[e + 1], s2 = eidx[e + 2], s3 = eidx[e + 3];
        float w0 = dinv[s0], w1 = dinv[s1], w2 = dinv[s2], w3 = dinv[s3];
        float4 h0 = ldh4(&h16[(size_t)s0 * HID + c4]);
        float4 h1 = ldh4(&h16[(size_t)s1 * HID + c4]);
        float4 h2 = ldh4(&h16[(size_t)s2 * HID + c4]);
        float4 h3 = ldh4(&h16[(size_t)s3 * HID + c4]);
        FMA_EDGE(h0, w0); FMA_EDGE(h1, w1); FMA_EDGE(h2, w2); FMA_EDGE(h3, w3);
        e += 4;
    }
    for (; e < e1; ++e) {
        int s0 = eidx[e];
        float w0 = dinv[s0];
        float4 h0 = ldh4(&h16[(size_t)s0 * HID + c4]);
        FMA_EDGE(h0, w0);
    }
    return acc;
}

__device__ __forceinline__ float4 gather_row_nw(const __half* __restrict__ h16,
                                                const int* __restrict__ eidx,
                                                int e0, int e1, int c4) {
    float4 acc = make_float4(0.f, 0.f, 0.f, 0.f);
    int e = e0;
    for (; e + 7 < e1; e += 8) {
        int s0 = eidx[e],     s1 = eidx[e + 1], s2 = eidx[e + 2], s3 = eidx[e + 3];
        int s4 = eidx[e + 4], s5 = eidx[e + 5], s6 = eidx[e + 6], s7 = eidx[e + 7];
        float4 h0 = ldh4(&h16[(size_t)s0 * HID + c4]);
        float4 h1 = ldh4(&h16[(size_t)s1 * HID + c4]);
        float4 h2 = ldh4(&h16[(size_t)s2 * HID + c4]);
        float4 h3 = ldh4(&h16[(size_t)s3 * HID + c4]);
        float4 h4 = ldh4(&h16[(size_t)s4 * HID + c4]);
        float4 h5 = ldh4(&h16[(size_t)s5 * HID + c4]);
        float4 h6 = ldh4(&h16[(size_t)s6 * HID + c4]);
        float4 h7 = ldh4(&h16[(size_t)s7 * HID + c4]);
        ADD_EDGE(h0); ADD_EDGE(h1); ADD_EDGE(h2); ADD_EDGE(h3);
        ADD_EDGE(h4); ADD_EDGE(h5); ADD_EDGE(h6); ADD_EDGE(h7);
    }
    if (e + 3 < e1) {
        int s0 = eidx[e], s1 = eidx[e + 1], s2 = eidx[e + 2], s3 = eidx[e + 3];
        float4 h0 = ldh4(&h16[(size_t)s0 * HID + c4]);
        float4 h1 = ldh4(&h16[(size_t)s1 * HID + c4]);
        float4 h2 = ldh4(&h16[(size_t)s2 * HID + c4]);
        float4 h3 = ldh4(&h16[(size_t)s3 * HID + c4]);
        ADD_EDGE(h0); ADD_EDGE(h1); ADD_EDGE(h2); ADD_EDGE(h3);
        e += 4;
    }
    for (; e < e1; ++e) {
        int s0 = eidx[e];
        float4 h0 = ldh4(&h16[(size_t)s0 * HID + c4]);
        ADD_EDGE(h0);
    }
    return acc;
}

template <int K>
__device__ __forceinline__ void gemm_tile(const float* __restrict__ X,
                                          const float* __restrict__ W,
                                          __half* __restrict__ H16,
                                          int tile, float* smem) {
    const int tid = threadIdx.x;
    const int rg  = tid >> 4;
    const int c4  = (tid & 15) * 4;
    const int r0  = tile * 64 + rg * 4;
    const bool full = (r0 + 3 < N_NODES);

    float4 a0 = {0,0,0,0}, a1 = {0,0,0,0}, a2 = {0,0,0,0}, a3 = {0,0,0,0};

    for (int kh = 0; kh < K; kh += 64) {
        __syncthreads();
        for (int i = tid; i < 1024; i += 256)
            ((float4*)smem)[i] = ((const float4*)(W + kh * 64))[i];
        __syncthreads();

        const float* Xb = X + (size_t)r0 * K + kh;
        #pragma unroll 4
        for (int k2 = 0; k2 < 64; k2 += 4) {
            float4 w0 = *(float4*)&smem[(k2 + 0) * 64 + c4];
            float4 w1 = *(float4*)&smem[(k2 + 1) * 64 + c4];
            float4 w2 = *(float4*)&smem[(k2 + 2) * 64 + c4];
            float4 w3 = *(float4*)&smem[(k2 + 3) * 64 + c4];
            float4 x0 = {0,0,0,0}, x1 = {0,0,0,0}, x2 = {0,0,0,0}, x3 = {0,0,0,0};
            if (full) {
                x0 = *(const float4*)&Xb[0 * (size_t)K + k2];
                x1 = *(const float4*)&Xb[1 * (size_t)K + k2];
                x2 = *(const float4*)&Xb[2 * (size_t)K + k2];
                x3 = *(const float4*)&Xb[3 * (size_t)K + k2];
            } else {
                if (r0 + 0 < N_NODES) x0 = *(const float4*)&Xb[0 * (size_t)K + k2];
                if (r0 + 1 < N_NODES) x1 = *(const float4*)&Xb[1 * (size_t)K + k2];
                if (r0 + 2 < N_NODES) x2 = *(const float4*)&Xb[2 * (size_t)K + k2];
                if (r0 + 3 < N_NODES) x3 = *(const float4*)&Xb[3 * (size_t)K + k2];
            }
            FMA_ROW(a0, x0);
            FMA_ROW(a1, x1);
            FMA_ROW(a2, x2);
            FMA_ROW(a3, x3);
        }
    }

    if (full) {
        sth4(&H16[(size_t)(r0 + 0) * HID + c4], a0);
        sth4(&H16[(size_t)(r0 + 1) * HID + c4], a1);
        sth4(&H16[(size_t)(r0 + 2) * HID + c4], a2);
        sth4(&H16[(size_t)(r0 + 3) * HID + c4], a3);
    } else {
        if (r0 + 0 < N_NODES) sth4(&H16[(size_t)(r0 + 0) * HID + c4], a0);
        if (r0 + 1 < N_NODES) sth4(&H16[(size_t)(r0 + 1) * HID + c4], a1);
        if (r0 + 2 < N_NODES) sth4(&H16[(size_t)(r0 + 2) * HID + c4], a2);
        if (r0 + 3 < N_NODES) sth4(&H16[(size_t)(r0 + 3) * HID + c4], a3);
    }
}

// ---- hist + per-graph counts: high-occupancy (no gemm in this kernel) ----
__global__ __launch_bounds__(256) void k_histcnt(const int* __restrict__ dst,
                                                 int* __restrict__ hist,   // [NBINS][NBLK]
                                                 const int* __restrict__ batch,
                                                 int* __restrict__ gcnt) {
    __shared__ int bins[NBINS];
    int bid = blockIdx.x;
    int tid = threadIdx.x;
    if (bid < NBLK) {
        for (int i = tid; i < NBINS; i += 256) bins[i] = 0;
        __syncthreads();
        #pragma unroll
        for (int it = 0; it < 4; ++it) {
            int base = bid * 4096 + it * 1024 + tid * 4;
            if (base < N_EDGES) {
                int4 d4 = *(const int4*)&dst[base];
                atomicAdd(&bins[d4.x >> 7], 1);
                atomicAdd(&bins[d4.y >> 7], 1);
                atomicAdd(&bins[d4.z >> 7], 1);
                atomicAdd(&bins[d4.w >> 7], 1);
            }
        }
        __syncthreads();
        for (int i = tid; i < NBINS; i += 256) hist[(size_t)i * NBLK + bid] = bins[i];
    } else {
        if (tid < NG) bins[tid] = 0;
        __syncthreads();
        int i = (bid - NBLK) * 256 + tid;
        if (i < N_NODES) atomicAdd(&bins[batch[i]], 1);
        __syncthreads();
        if (tid < NG && bins[tid] != 0) atomicAdd(&gcnt[tid], bins[tid]);
    }
}

// ---- scan L1: 391 blocks x 1024 over hist (400384 = 391*1024 exactly) ----
__global__ __launch_bounds__(1024) void k_bsum(const int* __restrict__ hist,
                                               int* __restrict__ bsum) {
    __shared__ int red[1024];
    int i = blockIdx.x * 1024 + threadIdx.x;
    red[threadIdx.x] = hist[i];
    __syncthreads();
    for (int off = 512; off > 0; off >>= 1) {
        if (threadIdx.x < off) red[threadIdx.x] += red[threadIdx.x + off];
        __syncthreads();
    }
    if (threadIdx.x == 0) bsum[blockIdx.x] = red[0];
}

__global__ __launch_bounds__(512) void k_scanb(const int* __restrict__ bsum,
                                               int* __restrict__ boff, int nb) {
    __shared__ int tmp[512];
    int t = threadIdx.x;
    int v = (t < nb) ? bsum[t] : 0;
    tmp[t] = v;
    __syncthreads();
    for (int off = 1; off < 512; off <<= 1) {
        int u = (t >= off) ? tmp[t - off] : 0;
        __syncthreads();
        tmp[t] += u;
        __syncthreads();
    }
    if (t < nb) boff[t] = tmp[t] - v;
}

// ---- scan L3: in-place exclusive scan of hist; emit bucketstart ----
__global__ __launch_bounds__(1024) void k_scanfin(int* __restrict__ hist,
                                                  const int* __restrict__ boff,
                                                  int* __restrict__ bucketstart) {
    __shared__ int tmp[1024];
    int i = blockIdx.x * 1024 + threadIdx.x;
    int t = threadIdx.x;
    int v = hist[i];
    tmp[t] = v;
    __syncthreads();
    for (int off = 1; off < 1024; off <<= 1) {
        int u = (t >= off) ? tmp[t - off] : 0;
        __syncthreads();
        tmp[t] += u;
        __syncthreads();
    }
    int excl = boff[blockIdx.x] + tmp[t] - v;
    hist[i] = excl;
    if (i % NBLK == 0) bucketstart[i / NBLK] = excl;   // i = bin*NBLK
}

// ---- fused: [gemm1 tiles | scatter blocks] — overlap x-read with scatter ----
__global__ __launch_bounds__(256) void k_gemmscatter(const float* __restrict__ X,
                                                     const float* __restrict__ W,
                                                     __half* __restrict__ H16,
                                                     const int* __restrict__ src,
                                                     const int* __restrict__ dst,
                                                     const int* __restrict__ hist,
                                                     int* __restrict__ ebuf) {
    __shared__ float smem[4096];   // 16 KB: gemm W-stage / scatter cursors (4KB)
    int bid = blockIdx.x;
    int tid = threadIdx.x;
    if (bid < GEMB) {
        gemm_tile<F_IN>(X, W, H16, bid, smem);
    } else {
        int cb = bid - GEMB;
        int* cur = (int*)smem;
        for (int i = tid; i < NBINS; i += 256) cur[i] = hist[(size_t)i * NBLK + cb];
        __syncthreads();
        #pragma unroll
        for (int it = 0; it < 4; ++it) {
            int base = cb * 4096 + it * 1024 + tid * 4;
            if (base < N_EDGES) {
                int4 s4 = *(const int4*)&src[base];
                int4 d4 = *(const int4*)&dst[base];
                int p0 = atomicAdd(&cur[d4.x >> 7], 1);
                int p1 = atomicAdd(&cur[d4.y >> 7], 1);
                int p2 = atomicAdd(&cur[d4.z >> 7], 1);
                int p3 = atomicAdd(&cur[d4.w >> 7], 1);
                ebuf[p0] = (s4.x << 7) | (d4.x & 127);
                ebuf[p1] = (s4.y << 7) | (d4.y & 127);
                ebuf[p2] = (s4.z << 7) | (d4.z & 127);
                ebuf[p3] = (s4.w << 7) | (d4.w & 127);
            }
        }
    }
}

// ---- per-bucket CSR: stage recs in LDS, count/scan 128 nodes, place in-place ----
__global__ __launch_bounds__(256) void k_bucketcsr(int* __restrict__ eidx,   // = ebuf
                                                   const int* __restrict__ bucketstart,
                                                   int* __restrict__ rowptr,
                                                   float* __restrict__ dinv) {
    __shared__ int lrec[4096];
    __shared__ int lcnt[128];
    __shared__ int lsum[128];
    __shared__ int lcur[128];
    int b = blockIdx.x;
    int tid = threadIdx.x;
    int s0 = bucketstart[b], s1 = bucketstart[b + 1];
    int cnt = s1 - s0;

    if (tid < 128) lcnt[tid] = 0;
    __syncthreads();
    for (int i = tid; i < cnt; i += 256) {
        int r = eidx[s0 + i];
        lrec[i] = r;
        atomicAdd(&lcnt[r & 127], 1);
    }
    __syncthreads();
    if (tid < 128) lsum[tid] = lcnt[tid];
    __syncthreads();
    for (int off = 1; off < 128; off <<= 1) {
        int u = 0;
        if (tid < 128 && tid >= off) u = lsum[tid - off];
        __syncthreads();
        if (tid < 128) lsum[tid] += u;
        __syncthreads();
    }
    if (tid < 128) {
        int excl = lsum[tid] - lcnt[tid];
        lcur[tid] = s0 + excl;
        int node = b * 128 + tid;
        if (node < N_NODES) {
            rowptr[node] = s0 + excl;
            dinv[node] = 1.0f / sqrtf((float)lcnt[tid] + 1.0f);
        }
    }
    __syncthreads();
    for (int i = tid; i < cnt; i += 256) {
        int r = lrec[i];
        int p = atomicAdd(&lcur[r & 127], 1);
        eidx[p] = r >> 7;
    }
    if (b == 0 && tid == 0) rowptr[N_NODES] = N_EDGES;
}

// ---- fused: gather L1 -> relu -> fp32 LDS -> gemm x W2 (global/L1) -> pre-scaled fp16 ----
__global__ __launch_bounds__(256) void k_gathergemm(const __half* __restrict__ h16,
                                                    const int* __restrict__ eidx,
                                                    const int* __restrict__ rowptr,
                                                    const float* __restrict__ dinv,
                                                    const float* __restrict__ bias,
                                                    const float* __restrict__ W2,
                                                    __half* __restrict__ Hout16) {
    __shared__ float Xl[64][66];
    const int tid  = threadIdx.x;
    const int ng4  = tid >> 4;
    const int tile = blockIdx.x;
    const int c4   = (tid & 15) * 4;

    float4 b = *(const float4*)&bias[c4];
    #pragma unroll
    for (int j = 0; j < 4; ++j) {
        int node = tile * 64 + ng4 * 4 + j;
        float4 r = make_float4(0.f, 0.f, 0.f, 0.f);
        if (node < N_NODES) {
            int e0 = rowptr[node], e1 = rowptr[node + 1];
            float4 acc = gather_row_w(h16, eidx, dinv, e0, e1, c4);
            float di = dinv[node];
            float4 hd = ldh4(&h16[(size_t)node * HID + c4]);
            r.x = fmaxf(fmaf(di, fmaf(di, hd.x, acc.x), b.x), 0.f);
            r.y = fmaxf(fmaf(di, fmaf(di, hd.y, acc.y), b.y), 0.f);
            r.z = fmaxf(fmaf(di, fmaf(di, hd.z, acc.z), b.z), 0.f);
            r.w = fmaxf(fmaf(di, fmaf(di, hd.w, acc.w), b.w), 0.f);
        }
        *(float4*)&Xl[ng4 * 4 + j][c4] = r;
    }
    __syncthreads();

    float4 a0 = {0,0,0,0}, a1 = {0,0,0,0}, a2 = {0,0,0,0}, a3 = {0,0,0,0};
    #pragma unroll 4
    for (int k2 = 0; k2 < 64; k2 += 4) {
        float4 w0 = *(const float4*)&W2[(k2 + 0) * 64 + c4];
        float4 w1 = *(const float4*)&W2[(k2 + 1) * 64 + c4];
        float4 w2 = *(const float4*)&W2[(k2 + 2) * 64 + c4];
        float4 w3 = *(const float4*)&W2[(k2 + 3) * 64 + c4];
        float4 x0 = *(float4*)&Xl[ng4 * 4 + 0][k2];
        float4 x1 = *(float4*)&Xl[ng4 * 4 + 1][k2];
        float4 x2 = *(float4*)&Xl[ng4 * 4 + 2][k2];
        float4 x3 = *(float4*)&Xl[ng4 * 4 + 3][k2];
        FMA_ROW(a0, x0);
        FMA_ROW(a1, x1);
        FMA_ROW(a2, x2);
        FMA_ROW(a3, x3);
    }

    const int r0 = tile * 64 + ng4 * 4;
    if (r0 + 0 < N_NODES) { float d0 = dinv[r0 + 0];
        a0.x *= d0; a0.y *= d0; a0.z *= d0; a0.w *= d0;
        sth4(&Hout16[(size_t)(r0 + 0) * HID + c4], a0); }
    if (r0 + 1 < N_NODES) { float d1 = dinv[r0 + 1];
        a1.x *= d1; a1.y *= d1; a1.z *= d1; a1.w *= d1;
        sth4(&Hout16[(size_t)(r0 + 1) * HID + c4], a1); }
    if (r0 + 2 < N_NODES) { float d2 = dinv[r0 + 2];
        a2.x *= d2; a2.y *= d2; a2.z *= d2; a2.w *= d2;
        sth4(&Hout16[(size_t)(r0 + 2) * HID + c4], a2); }
    if (r0 + 3 < N_NODES) { float d3 = dinv[r0 + 3];
        a3.x *= d3; a3.y *= d3; a3.z *= d3; a3.w *= d3;
        sth4(&Hout16[(size_t)(r0 + 3) * HID + c4], a3); }
}

// ---- fused: gather L2 (pre-scaled) -> relu -> fp32 LDS -> run-length pool ----
__global__ __launch_bounds__(256) void k_gatherpool(const __half* __restrict__ hw16,
                                                    const int* __restrict__ eidx,
                                                    const int* __restrict__ rowptr,
                                                    const float* __restrict__ dinv,
                                                    const float* __restrict__ bias,
                                                    const int* __restrict__ batch,
                                                    float* __restrict__ gsum) {
    __shared__ float Xl[64][66];
    __shared__ int bl[64];
    const int tid  = threadIdx.x;
    const int ng4  = tid >> 4;
    const int tile = blockIdx.x;
    const int c4   = (tid & 15) * 4;

    if (tid < 64) {
        int node = tile * 64 + tid;
        bl[tid] = (node < N_NODES) ? batch[node] : -1;
    }

    float4 b = *(const float4*)&bias[c4];
    #pragma unroll
    for (int j = 0; j < 4; ++j) {
        int node = tile * 64 + ng4 * 4 + j;
        float4 r = make_float4(0.f, 0.f, 0.f, 0.f);
        if (node < N_NODES) {
            int e0 = rowptr[node], e1 = rowptr[node + 1];
            float4 acc = gather_row_nw(hw16, eidx, e0, e1, c4);
            float di = dinv[node];
            float4 hw = ldh4(&hw16[(size_t)node * HID + c4]);
            r.x = fmaxf(fmaf(di, acc.x + hw.x, b.x), 0.f);
            r.y = fmaxf(fmaf(di, acc.y + hw.y, b.y), 0.f);
            r.z = fmaxf(fmaf(di, acc.z + hw.z, b.z), 0.f);
            r.w = fmaxf(fmaf(di, acc.w + hw.w, b.w), 0.f);
        }
        *(float4*)&Xl[ng4 * 4 + j][c4] = r;
    }
    __syncthreads();

    if (tid < 64) {
        int c = tid;
        float acc = 0.f;
        int gprev = bl[0];
        #pragma unroll 8
        for (int n = 0; n < 64; ++n) {
            int g = bl[n];
            if (g < 0) break;
            if (g != gprev) {
                unsafeAtomicAdd(&gsum[gprev * HID + c], acc);
                acc = 0.f;
                gprev = g;
            }
            acc += Xl[n][c];
        }
        if (gprev >= 0) unsafeAtomicAdd(&gsum[gprev * HID + c], acc);
    }
}

__global__ void k_out(const float* __restrict__ gsum, const int* __restrict__ gcnt,
                      const float* __restrict__ Wout, const float* __restrict__ bout,
                      float* __restrict__ out) {
    int g = threadIdx.x;
    if (g >= NG) return;
    float acc = 0.f;
    for (int c = 0; c < HID; ++c) acc += gsum[g * HID + c] * Wout[c];
    float cnt = fmaxf((float)gcnt[g], 1.0f);
    out[g] = acc / cnt + bout[0];
}

extern "C" void kernel_launch(void* const* d_in, const int* in_sizes, int n_in,
                              void* d_out, int out_size, void* d_ws, size_t ws_size,
                              hipStream_t stream) {
    const float* x    = (const float*)d_in[0];
    const int*   ei   = (const int*)d_in[1];
    const int*   batch= (const int*)d_in[2];
    const float* W1   = (const float*)d_in[3];
    const float* b1   = (const float*)d_in[4];
    const float* W2   = (const float*)d_in[5];
    const float* b2   = (const float*)d_in[6];
    const float* Wout = (const float*)d_in[7];
    const float* bout = (const float*)d_in[8];
    float* out = (float*)d_out;

    const int* src  = ei;
    const int* dstp = ei + N_EDGES;

    char* w = (char*)d_ws;
    int*    hist  = (int*)w;    w += (size_t)NBINS * NBLK * 4;
    int*    bstrt = (int*)w;    w += (size_t)(NBINS + 8) * 4;
    int*    gcnt  = (int*)w;    w += (size_t)NG * 4;
    int*    bsum  = (int*)w;    w += (size_t)512 * 4;
    int*    boff  = (int*)w;    w += (size_t)512 * 4;
    int*    rowptr= (int*)w;    w += (size_t)(N_NODES + 4) * 4;
    float*  dinv  = (float*)w;  w += (size_t)N_NODES * 4;
    float*  gsum  = (float*)w;  w += (size_t)NG * HID * 4;
    int*    eidx  = (int*)w;    w += (size_t)N_EDGES * 4;
    __half* bufA16= (__half*)w; w += (size_t)N_NODES * HID * 2;
    __half* bufB16= (__half*)w; w += (size_t)N_NODES * HID * 2;

    hipMemsetAsync(gcnt, 0, (size_t)NG * 4, stream);
    hipMemsetAsync(gsum, 0, (size_t)NG * HID * 4, stream);

    // high-occupancy bucket histogram + per-graph counts (LDS bins only)
    k_histcnt<<<NBLK + CNTB, 256, 0, stream>>>(dstp, hist, batch, gcnt);
    // linear exclusive scan of hist
    k_bsum   <<<NBLK, 1024, 0, stream>>>(hist, bsum);
    k_scanb  <<<1, 512, 0, stream>>>(bsum, boff, NBLK);
    k_scanfin<<<NBLK, 1024, 0, stream>>>(hist, boff, bstrt);
    // gemm1 overlapped with bucket-grouped scatter (LDS atomic-returns only)
    k_gemmscatter<<<GEMB + NBLK, 256, 0, stream>>>(x, W1, bufA16, src, dstp, hist, eidx);
    // per-bucket CSR finalize
    k_bucketcsr<<<BUCKETS, 256, 0, stream>>>(eidx, bstrt, rowptr, dinv);

    // Layer-1 aggregation fused with layer-2 GEMM (writes pre-scaled fp16)
    k_gathergemm<<<GEMB, 256, 0, stream>>>(bufA16, eidx, rowptr, dinv, b1, W2, bufB16);
    // Layer-2 aggregation fused with mean-pool partials
    k_gatherpool<<<GEMB, 256, 0, stream>>>(bufB16, eidx, rowptr, dinv, b2, batch, gsum);

    k_out<<<1, 128, 0, stream>>>(gsum, gcnt, Wout, bout, out);
}